// Round 1
// baseline (2041.638 us; speedup 1.0000x reference)
//
#include <hip/hip_runtime.h>
#include <math.h>

#define NN 50000
#define NE 800000

// ---------------- CSR build ----------------

__global__ void count_edges_k(const int* __restrict__ edst, int* __restrict__ counts, int e) {
    int i = blockIdx.x * blockDim.x + threadIdx.x;
    if (i < e) atomicAdd(&counts[edst[i]], 1);
}

__global__ __launch_bounds__(1024) void scan_k(const int* __restrict__ counts,
                                               int* __restrict__ row_start,
                                               int* __restrict__ cursor,
                                               float* __restrict__ inv_deg, int n) {
    __shared__ int sdata[1024];
    __shared__ int s_running;
    int tid = threadIdx.x;
    if (tid == 0) s_running = 0;
    __syncthreads();
    for (int base = 0; base < n; base += 1024) {
        int i = base + tid;
        int v = (i < n) ? counts[i] : 0;
        sdata[tid] = v;
        __syncthreads();
        for (int off = 1; off < 1024; off <<= 1) {
            int t = (tid >= off) ? sdata[tid - off] : 0;
            __syncthreads();
            sdata[tid] += t;
            __syncthreads();
        }
        int incl = sdata[tid];
        int excl = incl - v;
        int run = s_running;
        __syncthreads();
        if (tid == 1023) s_running = run + incl;
        __syncthreads();
        if (i < n) {
            row_start[i] = run + excl;
            cursor[i]    = run + excl;
            inv_deg[i]   = 1.0f / fmaxf((float)v, 1.0f);
        }
    }
    if (tid == 0) row_start[n] = s_running;
}

__global__ void fill_csr_k(const int* __restrict__ esrc, const int* __restrict__ edst,
                           int* __restrict__ cursor, int* __restrict__ csr_src, int e) {
    int i = blockIdx.x * blockDim.x + threadIdx.x;
    if (i < e) {
        int pos = atomicAdd(&cursor[edst[i]], 1);
        csr_src[pos] = esrc[i];
    }
}

// ---------------- dual GEMM: V = A@W1, R = A@W2 ----------------
// A: [n, K] row-major, W: [K, M] row-major, V/R: [n, M]
template<int M>
__global__ __launch_bounds__(256) void gemm_dual_k(const float* __restrict__ A, int K,
                                                   const float* __restrict__ W1,
                                                   const float* __restrict__ W2,
                                                   float* __restrict__ V,
                                                   float* __restrict__ R, int n) {
    constexpr int CT = M / 4;       // col-thread count (each thread: 4 consecutive cols)
    constexpr int RT = 256 / CT;    // row-thread count (each thread: 4 rows)
    constexpr int ROWS = RT * 4;
    __shared__ float As[ROWS][68];  // pad 68 to spread banks; 68*4 % 16 == 0 (f4-aligned)

    int tid = threadIdx.x;
    int tx = tid % CT, ty = tid / CT;
    int c0 = tx * 4;
    int row0 = blockIdx.x * ROWS;

    float acc1[4][4] = {};
    float acc2[4][4] = {};

    for (int kc = 0; kc < K; kc += 64) {
        __syncthreads();
        for (int l = tid; l < ROWS * 16; l += 256) {
            int r = l >> 4, k4 = (l & 15) << 2;
            int row = row0 + r;
            float4 a = (row < n) ? *(const float4*)(A + (size_t)row * K + kc + k4)
                                 : make_float4(0.f, 0.f, 0.f, 0.f);
            *(float4*)(&As[r][k4]) = a;
        }
        __syncthreads();

        for (int k4 = 0; k4 < 64; k4 += 4) {
            float4 av[4];
            #pragma unroll
            for (int i = 0; i < 4; ++i) av[i] = *(const float4*)(&As[ty * 4 + i][k4]);
            #pragma unroll
            for (int j = 0; j < 4; ++j) {
                const int k = kc + k4 + j;
                float4 w1 = *(const float4*)(W1 + (size_t)k * M + c0);
                float4 w2 = *(const float4*)(W2 + (size_t)k * M + c0);
                #pragma unroll
                for (int i = 0; i < 4; ++i) {
                    float a = (j == 0) ? av[i].x : (j == 1) ? av[i].y : (j == 2) ? av[i].z : av[i].w;
                    acc1[i][0] = fmaf(a, w1.x, acc1[i][0]);
                    acc1[i][1] = fmaf(a, w1.y, acc1[i][1]);
                    acc1[i][2] = fmaf(a, w1.z, acc1[i][2]);
                    acc1[i][3] = fmaf(a, w1.w, acc1[i][3]);
                    acc2[i][0] = fmaf(a, w2.x, acc2[i][0]);
                    acc2[i][1] = fmaf(a, w2.y, acc2[i][1]);
                    acc2[i][2] = fmaf(a, w2.z, acc2[i][2]);
                    acc2[i][3] = fmaf(a, w2.w, acc2[i][3]);
                }
            }
        }
    }

    #pragma unroll
    for (int i = 0; i < 4; ++i) {
        int row = row0 + ty * 4 + i;
        if (row < n) {
            *(float4*)(V + (size_t)row * M + c0) = make_float4(acc1[i][0], acc1[i][1], acc1[i][2], acc1[i][3]);
            *(float4*)(R + (size_t)row * M + c0) = make_float4(acc2[i][0], acc2[i][1], acc2[i][2], acc2[i][3]);
        }
    }
}

// ---------------- per-dst aggregation + combine ----------------
// out[dst, c] = act( (sum_{src in N(dst)} V[src,c]) * inv_deg[dst] + bias[c] + R[dst,c] )
// one wave per dst node; M = VW*64. ACT: 0=none, 1=relu, 2=sigmoid
template<int VW, int ACT>
__global__ __launch_bounds__(256) void agg_combine_k(const float* __restrict__ V,
                                                     const float* __restrict__ R,
                                                     const float* __restrict__ bias,
                                                     const float* __restrict__ inv_deg,
                                                     const int* __restrict__ row_start,
                                                     const int* __restrict__ csr_src,
                                                     float* __restrict__ out, int ld_out, int n) {
    constexpr int M = VW * 64;
    int wid  = (blockIdx.x * blockDim.x + threadIdx.x) >> 6;  // global wave id = dst node
    int lane = threadIdx.x & 63;
    if (wid >= n) return;
    int dst = wid;
    int c = lane * VW;

    float acc[VW];
    #pragma unroll
    for (int q = 0; q < VW; ++q) acc[q] = 0.f;

    int s = row_start[dst], e = row_start[dst + 1];
    for (int j = s; j < e; ++j) {
        int src = csr_src[j];
        const float* vp = V + (size_t)src * M + c;
        if constexpr (VW == 4) {
            float4 v4 = *(const float4*)vp;
            acc[0] += v4.x; acc[1] += v4.y; acc[2] += v4.z; acc[3] += v4.w;
        } else if constexpr (VW == 2) {
            float2 v2 = *(const float2*)vp;
            acc[0] += v2.x; acc[1] += v2.y;
        } else {
            acc[0] += *vp;
        }
    }

    float inv = inv_deg[dst];
    #pragma unroll
    for (int q = 0; q < VW; ++q) {
        float v = acc[q] * inv;
        if (bias) v += bias[c + q];
        if (R)    v += R[(size_t)dst * M + c + q];
        if constexpr (ACT == 1) v = fmaxf(v, 0.f);
        else if constexpr (ACT == 2) v = 1.f / (1.f + expf(-v));
        out[(size_t)dst * ld_out + c + q] = v;
    }
}

// ---------------- heads + cross-entropy ----------------

template<int C>
__device__ inline float head_one(const float* __restrict__ ah, const float* __restrict__ hh,
                                 const float* __restrict__ Wl, const float* __restrict__ bl,
                                 const float* __restrict__ Wr, int label) {
    float z[C];
    #pragma unroll
    for (int c = 0; c < C; ++c) z[c] = bl[c];
    for (int d = 0; d < 64; ++d) {
        float a = ah[d], h = hh[d];
        #pragma unroll
        for (int c = 0; c < C; ++c)
            z[c] = fmaf(a, Wl[d * C + c], fmaf(h, Wr[d * C + c], z[c]));
    }
    float m = -1e30f;
    #pragma unroll
    for (int c = 0; c < C; ++c) { z[c] = 1.f / (1.f + expf(-z[c])); m = fmaxf(m, z[c]); }
    float ssum = 0.f, zl = 0.f;
    #pragma unroll
    for (int c = 0; c < C; ++c) { ssum += expf(z[c] - m); if (c == label) zl = z[c]; }
    return (logf(ssum) + m) - zl;   // = -(logp[label])
}

__global__ __launch_bounds__(256) void head_ce_k(const float* __restrict__ Ah,
                                                 const float* __restrict__ hk,
                                                 const float* __restrict__ Wl1, const float* __restrict__ b1, const float* __restrict__ Wr1,
                                                 const float* __restrict__ Wl2, const float* __restrict__ b2, const float* __restrict__ Wr2,
                                                 const float* __restrict__ Wl3, const float* __restrict__ b3, const float* __restrict__ Wr3,
                                                 const int* __restrict__ y,
                                                 float* __restrict__ loss_acc, int n) {
    int nidx = blockIdx.x * blockDim.x + threadIdx.x;
    float lsum = 0.f;
    if (nidx < n) {
        const float* ah = Ah + (size_t)nidx * 64;
        const float* hh = hk + (size_t)nidx * 64;
        lsum += head_one<12>(ah, hh, Wl1, b1, Wr1, y[nidx * 3 + 0]);
        lsum += head_one<8 >(ah, hh, Wl2, b2, Wr2, y[nidx * 3 + 1]);
        lsum += head_one<5 >(ah, hh, Wl3, b3, Wr3, y[nidx * 3 + 2]);
    }
    // wave64 reduce + block reduce + one atomic per block
    for (int off = 32; off > 0; off >>= 1) lsum += __shfl_down(lsum, off);
    __shared__ float ssum[4];
    int wv = threadIdx.x >> 6, ln = threadIdx.x & 63;
    if (ln == 0) ssum[wv] = lsum;
    __syncthreads();
    if (threadIdx.x == 0) atomicAdd(loss_acc, ssum[0] + ssum[1] + ssum[2] + ssum[3]);
}

__global__ void finalize_k(const float* __restrict__ loss_acc, float* __restrict__ out, int n) {
    out[0] = loss_acc[0] * (1.0f / (float)n);
}

// ---------------- host ----------------

extern "C" void kernel_launch(void* const* d_in, const int* in_sizes, int n_in,
                              void* d_out, int out_size, void* d_ws, size_t ws_size,
                              hipStream_t stream) {
    const float* X    = (const float*)d_in[0];
    const int*   esrc = (const int*)d_in[1];
    const int*   edst = (const int*)d_in[2];
    const int*   y    = (const int*)d_in[3];
    const float* Wl_i[2] = {(const float*)d_in[4], (const float*)d_in[7]};
    const float* bl_i[2] = {(const float*)d_in[5], (const float*)d_in[8]};
    const float* Wr_i[2] = {(const float*)d_in[6], (const float*)d_in[9]};
    const float* Wl_m = (const float*)d_in[10], *bl_m = (const float*)d_in[11], *Wr_m = (const float*)d_in[12];
    const float* Wl_o = (const float*)d_in[13], *bl_o = (const float*)d_in[14], *Wr_o = (const float*)d_in[15];
    const float* Wl_t1 = (const float*)d_in[16], *bl_t1 = (const float*)d_in[17], *Wr_t1 = (const float*)d_in[18];
    const float* Wl_t2 = (const float*)d_in[19], *bl_t2 = (const float*)d_in[20], *Wr_t2 = (const float*)d_in[21];
    const float* Wl_t3 = (const float*)d_in[22], *bl_t3 = (const float*)d_in[23], *Wr_t3 = (const float*)d_in[24];

    const int N = NN, E = NE;
    char* p = (char*)d_ws;
    auto alloc = [&](size_t bytes) -> char* {
        char* r = p;
        p += (bytes + 255) & ~(size_t)255;
        return r;
    };
    int*   counts    = (int*)alloc((size_t)N * 4);
    int*   row_start = (int*)alloc((size_t)(N + 1) * 4);
    int*   cursor    = (int*)alloc((size_t)N * 4);
    int*   csr_src   = (int*)alloc((size_t)E * 4);
    float* inv_deg   = (float*)alloc((size_t)N * 4);
    float* loss_acc  = (float*)alloc(256);
    float* V  = (float*)alloc((size_t)N * 256 * 4);
    float* R  = (float*)alloc((size_t)N * 256 * 4);
    float* xk = (float*)alloc((size_t)N * 256 * 4);
    float* hk = (float*)alloc((size_t)N * 64 * 4);
    float* Ah = (float*)alloc((size_t)N * 64 * 4);

    hipMemsetAsync(counts, 0, (size_t)N * 4, stream);
    hipMemsetAsync(loss_acc, 0, 4, stream);
    count_edges_k<<<(E + 255) / 256, 256, 0, stream>>>(edst, counts, E);
    scan_k<<<1, 1024, 0, stream>>>(counts, row_start, cursor, inv_deg, N);
    fill_csr_k<<<(E + 255) / 256, 256, 0, stream>>>(esrc, edst, cursor, csr_src, E);

    for (int k = 0; k < 2; ++k) {
        // input channels -> xk[:,0:128] and xk[:,128:256]
        for (int ch = 0; ch < 2; ++ch) {
            const float* Xc = X + (size_t)(k * 2 + ch) * N * 128;
            gemm_dual_k<128><<<(N + 31) / 32, 256, 0, stream>>>(Xc, 128, Wl_i[ch], Wr_i[ch], V, R, N);
            agg_combine_k<2, 1><<<(N + 3) / 4, 256, 0, stream>>>(V, R, bl_i[ch], inv_deg, row_start, csr_src,
                                                                 xk + ch * 128, 256, N);
        }
        // mid layer [256->256], output overwrites xk (safe: xk no longer read)
        gemm_dual_k<256><<<(N + 15) / 16, 256, 0, stream>>>(xk, 256, Wl_m, Wr_m, V, R, N);
        agg_combine_k<4, 1><<<(N + 3) / 4, 256, 0, stream>>>(V, R, bl_m, inv_deg, row_start, csr_src,
                                                             xk, 256, N);
        // out layer [256->64], sigmoid -> hk
        gemm_dual_k<64><<<(N + 63) / 64, 256, 0, stream>>>(xk, 256, Wl_o, Wr_o, V, R, N);
        agg_combine_k<1, 2><<<(N + 3) / 4, 256, 0, stream>>>(V, R, bl_o, inv_deg, row_start, csr_src,
                                                             hk, 64, N);
        // shared aggregation of hk for all three heads
        agg_combine_k<1, 0><<<(N + 3) / 4, 256, 0, stream>>>(hk, nullptr, nullptr, inv_deg, row_start, csr_src,
                                                             Ah, 64, N);
        // heads + CE
        head_ce_k<<<(N + 255) / 256, 256, 0, stream>>>(Ah, hk,
            Wl_t1 + (size_t)k * 64 * 12, bl_t1 + (size_t)k * 12, Wr_t1 + (size_t)k * 64 * 12,
            Wl_t2 + (size_t)k * 64 * 8,  bl_t2 + (size_t)k * 8,  Wr_t2 + (size_t)k * 64 * 8,
            Wl_t3 + (size_t)k * 64 * 5,  bl_t3 + (size_t)k * 5,  Wr_t3 + (size_t)k * 64 * 5,
            y + (size_t)k * N * 3, loss_acc, N);
    }
    finalize_k<<<1, 1, 0, stream>>>(loss_acc, (float*)d_out, N);
}

// Round 2
// 1337.428 us; speedup vs baseline: 1.5265x; 1.5265x over previous
//
#include <hip/hip_runtime.h>
#include <math.h>

#define NN 50000
#define NE 800000

typedef short bf16x8 __attribute__((ext_vector_type(8)));
typedef float f32x4 __attribute__((ext_vector_type(4)));

__device__ inline ushort f2bf(float f) {
    union { float f; uint u; } v; v.f = f;
    uint r = v.u + 0x7FFFu + ((v.u >> 16) & 1u);
    return (ushort)(r >> 16);
}
__device__ inline float bf2f(ushort h) {
    union { uint u; float f; } v; v.u = ((uint)h) << 16;
    return v.f;
}

// ---------------- CSR build ----------------

__global__ void count_edges_k(const int* __restrict__ edst, int* __restrict__ counts, int e) {
    int i = blockIdx.x * blockDim.x + threadIdx.x;
    if (i < e) atomicAdd(&counts[edst[i]], 1);
}

__global__ __launch_bounds__(1024) void scan_k(const int* __restrict__ counts,
                                               int* __restrict__ row_start,
                                               int* __restrict__ cursor,
                                               float* __restrict__ inv_deg, int n) {
    __shared__ int sdata[1024];
    __shared__ int s_running;
    int tid = threadIdx.x;
    if (tid == 0) s_running = 0;
    __syncthreads();
    for (int base = 0; base < n; base += 1024) {
        int i = base + tid;
        int v = (i < n) ? counts[i] : 0;
        sdata[tid] = v;
        __syncthreads();
        for (int off = 1; off < 1024; off <<= 1) {
            int t = (tid >= off) ? sdata[tid - off] : 0;
            __syncthreads();
            sdata[tid] += t;
            __syncthreads();
        }
        int incl = sdata[tid];
        int excl = incl - v;
        int run = s_running;
        __syncthreads();
        if (tid == 1023) s_running = run + incl;
        __syncthreads();
        if (i < n) {
            row_start[i] = run + excl;
            cursor[i]    = run + excl;
            inv_deg[i]   = 1.0f / fmaxf((float)v, 1.0f);
        }
    }
    if (tid == 0) row_start[n] = s_running;
}

__global__ void fill_csr_k(const int* __restrict__ esrc, const int* __restrict__ edst,
                           int* __restrict__ cursor, int* __restrict__ csr_src, int e) {
    int i = blockIdx.x * blockDim.x + threadIdx.x;
    if (i < e) {
        int pos = atomicAdd(&cursor[edst[i]], 1);
        csr_src[pos] = esrc[i];
    }
}

// ---------------- weight prep: Wt[c][k] = bf16(c < M ? W1[k][c] : W2[k][c-M]) ----------------

__global__ void prep_w_k(const float* __restrict__ W1, const float* __restrict__ W2,
                         ushort* __restrict__ Wt, int K, int M) {
    int i = blockIdx.x * blockDim.x + threadIdx.x;
    int tot = 2 * M * K;
    if (i >= tot) return;
    int c = i / K, k = i - c * K;
    float v = (c < M) ? W1[(size_t)k * M + c] : W2[(size_t)k * M + (c - M)];
    Wt[i] = f2bf(v);
}

// ---------------- MFMA GEMM: C[n, 2M] = A[n,K] @ Wt^T ; cols<M -> V (bf16), cols>=M -> R (f32) ---
// block tile 64 (rows) x 128 (cols), 4 waves as 2x2, each wave 32x64. BK=32.
// LDS rows padded to stride 40 halves (80B) -> 2-way bank aliasing only (free).

template<bool A_FP32>
__global__ __launch_bounds__(256) void gemm_mfma_k(const void* __restrict__ Av, int K,
                                                   const ushort* __restrict__ Wt,
                                                   ushort* __restrict__ V,
                                                   float* __restrict__ Rr,
                                                   int M, int n) {
    __shared__ __align__(16) ushort As[64 * 40];
    __shared__ __align__(16) ushort Bs[128 * 40];
    int tid = threadIdx.x;
    int row0 = blockIdx.x * 64;
    int col0 = blockIdx.y * 128;
    int lane = tid & 63, wid = tid >> 6;
    int wm = wid & 1, wn = wid >> 1;
    int lrow = lane & 15, lko = (lane >> 4) * 8;

    f32x4 acc[2][4];
    #pragma unroll
    for (int i = 0; i < 2; ++i)
        #pragma unroll
        for (int j = 0; j < 4; ++j)
            acc[i][j] = (f32x4){0.f, 0.f, 0.f, 0.f};

    for (int kc = 0; kc < K; kc += 32) {
        __syncthreads();
        if constexpr (A_FP32) {
            const float* A = (const float*)Av;
            #pragma unroll
            for (int l = tid; l < 512; l += 256) {
                int r = l >> 3, s = l & 7;
                int rg = row0 + r;
                float4 a = (rg < n) ? *(const float4*)(A + (size_t)rg * K + kc + s * 4)
                                    : make_float4(0.f, 0.f, 0.f, 0.f);
                ushort* dst = &As[r * 40 + s * 4];
                dst[0] = f2bf(a.x); dst[1] = f2bf(a.y); dst[2] = f2bf(a.z); dst[3] = f2bf(a.w);
            }
        } else {
            const ushort* A = (const ushort*)Av;
            int r = tid >> 2, s = tid & 3;
            int rg = row0 + r;
            uint4 a = (rg < n) ? *(const uint4*)(A + (size_t)rg * K + kc + s * 8)
                               : make_uint4(0u, 0u, 0u, 0u);
            *(uint4*)(&As[r * 40 + s * 8]) = a;
        }
        #pragma unroll
        for (int l = tid; l < 512; l += 256) {
            int r = l >> 2, s = l & 3;
            int cg = col0 + r;
            *(uint4*)(&Bs[r * 40 + s * 8]) = *(const uint4*)(Wt + (size_t)cg * K + kc + s * 8);
        }
        __syncthreads();

        bf16x8 af[2], bfr[4];
        #pragma unroll
        for (int i = 0; i < 2; ++i)
            af[i] = *(const bf16x8*)(&As[(wm * 32 + i * 16 + lrow) * 40 + lko]);
        #pragma unroll
        for (int j = 0; j < 4; ++j)
            bfr[j] = *(const bf16x8*)(&Bs[(wn * 64 + j * 16 + lrow) * 40 + lko]);
        #pragma unroll
        for (int i = 0; i < 2; ++i)
            #pragma unroll
            for (int j = 0; j < 4; ++j)
                acc[i][j] = __builtin_amdgcn_mfma_f32_16x16x32_bf16(af[i], bfr[j], acc[i][j], 0, 0, 0);
    }

    #pragma unroll
    for (int i = 0; i < 2; ++i) {
        int rbase = row0 + wm * 32 + i * 16 + (lane >> 4) * 4;
        #pragma unroll
        for (int j = 0; j < 4; ++j) {
            int cg = col0 + wn * 64 + j * 16 + lrow;
            #pragma unroll
            for (int q = 0; q < 4; ++q) {
                int rg = rbase + q;
                if (rg < n) {
                    float v = acc[i][j][q];
                    if (cg < M) V[(size_t)rg * M + cg] = f2bf(v);
                    else        Rr[(size_t)rg * M + (cg - M)] = v;
                }
            }
        }
    }
}

// ---------------- per-dst aggregation + combine ----------------
// out[dst,c] = act( (sum_{src in N(dst)} V[src,c]) * inv_deg[dst] + bias[c] + R[dst,c] )
// one wave per dst; M = VW*64. ACT: 0=none 1=relu 2=sigmoid. VBF: V is bf16. OBF: out is bf16.

template<int VW, int ACT, bool VBF, bool OBF>
__global__ __launch_bounds__(256) void agg_k(const void* __restrict__ Vv,
                                             const float* __restrict__ Rr,
                                             const float* __restrict__ bias,
                                             const float* __restrict__ inv_deg,
                                             const int* __restrict__ row_start,
                                             const int* __restrict__ csr_src,
                                             void* __restrict__ outv, int ld_out, int n) {
    constexpr int M = VW * 64;
    int wid  = (blockIdx.x * blockDim.x + threadIdx.x) >> 6;
    int lane = threadIdx.x & 63;
    if (wid >= n) return;
    int dst = wid;
    int c = lane * VW;

    float acc[VW];
    #pragma unroll
    for (int q = 0; q < VW; ++q) acc[q] = 0.f;

    int s = row_start[dst], e = row_start[dst + 1];
    for (int j = s; j < e; ++j) {
        int src = csr_src[j];
        if constexpr (VBF) {
            const ushort* vp = (const ushort*)Vv + (size_t)src * M + c;
            if constexpr (VW == 4) {
                ushort4 v4 = *(const ushort4*)vp;
                acc[0] += bf2f(v4.x); acc[1] += bf2f(v4.y); acc[2] += bf2f(v4.z); acc[3] += bf2f(v4.w);
            } else if constexpr (VW == 2) {
                uint w = *(const uint*)vp;
                acc[0] += bf2f((ushort)(w & 0xFFFF)); acc[1] += bf2f((ushort)(w >> 16));
            } else {
                acc[0] += bf2f(*vp);
            }
        } else {
            const float* vp = (const float*)Vv + (size_t)src * M + c;
            if constexpr (VW == 4) {
                float4 v4 = *(const float4*)vp;
                acc[0] += v4.x; acc[1] += v4.y; acc[2] += v4.z; acc[3] += v4.w;
            } else if constexpr (VW == 2) {
                float2 v2 = *(const float2*)vp;
                acc[0] += v2.x; acc[1] += v2.y;
            } else {
                acc[0] += *vp;
            }
        }
    }

    float inv = inv_deg[dst];
    float r[VW];
    #pragma unroll
    for (int q = 0; q < VW; ++q) {
        float v = acc[q] * inv;
        if (bias) v += bias[c + q];
        if (Rr)   v += Rr[(size_t)dst * M + c + q];
        if constexpr (ACT == 1) v = fmaxf(v, 0.f);
        else if constexpr (ACT == 2) v = 1.f / (1.f + expf(-v));
        r[q] = v;
    }
    if constexpr (OBF) {
        ushort* op = (ushort*)outv + (size_t)dst * ld_out + c;
        if constexpr (VW == 4) {
            ushort4 o; o.x = f2bf(r[0]); o.y = f2bf(r[1]); o.z = f2bf(r[2]); o.w = f2bf(r[3]);
            *(ushort4*)op = o;
        } else if constexpr (VW == 2) {
            uint o = (uint)f2bf(r[0]) | ((uint)f2bf(r[1]) << 16);
            *(uint*)op = o;
        } else {
            *op = f2bf(r[0]);
        }
    } else {
        float* op = (float*)outv + (size_t)dst * ld_out + c;
        #pragma unroll
        for (int q = 0; q < VW; ++q) op[q] = r[q];
    }
}

// ---------------- heads + cross-entropy ----------------

template<int C>
__device__ inline float head_one(const float* __restrict__ ah, const float* __restrict__ hh,
                                 const float* __restrict__ Wl, const float* __restrict__ bl,
                                 const float* __restrict__ Wr, int label) {
    float z[C];
    #pragma unroll
    for (int c = 0; c < C; ++c) z[c] = bl[c];
    for (int d = 0; d < 64; ++d) {
        float a = ah[d], h = hh[d];
        #pragma unroll
        for (int c = 0; c < C; ++c)
            z[c] = fmaf(a, Wl[d * C + c], fmaf(h, Wr[d * C + c], z[c]));
    }
    float m = -1e30f;
    #pragma unroll
    for (int c = 0; c < C; ++c) { z[c] = 1.f / (1.f + expf(-z[c])); m = fmaxf(m, z[c]); }
    float ssum = 0.f, zl = 0.f;
    #pragma unroll
    for (int c = 0; c < C; ++c) { ssum += expf(z[c] - m); if (c == label) zl = z[c]; }
    return (logf(ssum) + m) - zl;
}

__global__ __launch_bounds__(256) void head_ce_k(const float* __restrict__ Ah,
                                                 const float* __restrict__ hk,
                                                 const float* __restrict__ Wl1, const float* __restrict__ b1, const float* __restrict__ Wr1,
                                                 const float* __restrict__ Wl2, const float* __restrict__ b2, const float* __restrict__ Wr2,
                                                 const float* __restrict__ Wl3, const float* __restrict__ b3, const float* __restrict__ Wr3,
                                                 const int* __restrict__ y,
                                                 float* __restrict__ loss_acc, int n) {
    int nidx = blockIdx.x * blockDim.x + threadIdx.x;
    float lsum = 0.f;
    if (nidx < n) {
        const float* ah = Ah + (size_t)nidx * 64;
        const float* hh = hk + (size_t)nidx * 64;
        lsum += head_one<12>(ah, hh, Wl1, b1, Wr1, y[nidx * 3 + 0]);
        lsum += head_one<8 >(ah, hh, Wl2, b2, Wr2, y[nidx * 3 + 1]);
        lsum += head_one<5 >(ah, hh, Wl3, b3, Wr3, y[nidx * 3 + 2]);
    }
    for (int off = 32; off > 0; off >>= 1) lsum += __shfl_down(lsum, off);
    __shared__ float ssum[4];
    int wv = threadIdx.x >> 6, ln = threadIdx.x & 63;
    if (ln == 0) ssum[wv] = lsum;
    __syncthreads();
    if (threadIdx.x == 0) atomicAdd(loss_acc, ssum[0] + ssum[1] + ssum[2] + ssum[3]);
}

__global__ void finalize_k(const float* __restrict__ loss_acc, float* __restrict__ out, int n) {
    out[0] = loss_acc[0] * (1.0f / (float)n);
}

// ---------------- host ----------------

extern "C" void kernel_launch(void* const* d_in, const int* in_sizes, int n_in,
                              void* d_out, int out_size, void* d_ws, size_t ws_size,
                              hipStream_t stream) {
    const float* X    = (const float*)d_in[0];
    const int*   esrc = (const int*)d_in[1];
    const int*   edst = (const int*)d_in[2];
    const int*   y    = (const int*)d_in[3];
    const float* Wl_i[2] = {(const float*)d_in[4], (const float*)d_in[7]};
    const float* bl_i[2] = {(const float*)d_in[5], (const float*)d_in[8]};
    const float* Wr_i[2] = {(const float*)d_in[6], (const float*)d_in[9]};
    const float* Wl_m = (const float*)d_in[10], *bl_m = (const float*)d_in[11], *Wr_m = (const float*)d_in[12];
    const float* Wl_o = (const float*)d_in[13], *bl_o = (const float*)d_in[14], *Wr_o = (const float*)d_in[15];
    const float* Wl_t1 = (const float*)d_in[16], *bl_t1 = (const float*)d_in[17], *Wr_t1 = (const float*)d_in[18];
    const float* Wl_t2 = (const float*)d_in[19], *bl_t2 = (const float*)d_in[20], *Wr_t2 = (const float*)d_in[21];
    const float* Wl_t3 = (const float*)d_in[22], *bl_t3 = (const float*)d_in[23], *Wr_t3 = (const float*)d_in[24];

    const int N = NN, E = NE;
    char* p = (char*)d_ws;
    auto alloc = [&](size_t bytes) -> char* {
        char* r = p;
        p += (bytes + 255) & ~(size_t)255;
        return r;
    };
    int*    counts    = (int*)alloc((size_t)N * 4);
    int*    row_start = (int*)alloc((size_t)(N + 1) * 4);
    int*    cursor    = (int*)alloc((size_t)N * 4);
    int*    csr_src   = (int*)alloc((size_t)E * 4);
    float*  inv_deg   = (float*)alloc((size_t)N * 4);
    float*  loss_acc  = (float*)alloc(256);
    ushort* V    = (ushort*)alloc((size_t)N * 256 * 2);   // bf16 agg operand
    float*  R    = (float*)alloc((size_t)N * 256 * 4);    // fp32 residual
    ushort* xk   = (ushort*)alloc((size_t)N * 256 * 2);   // bf16 activations
    float*  hk   = (float*)alloc((size_t)N * 64 * 4);
    float*  Ah   = (float*)alloc((size_t)N * 64 * 4);
    ushort* Wt_i0 = (ushort*)alloc((size_t)256 * 128 * 2);
    ushort* Wt_i1 = (ushort*)alloc((size_t)256 * 128 * 2);
    ushort* Wt_m  = (ushort*)alloc((size_t)512 * 256 * 2);
    ushort* Wt_o  = (ushort*)alloc((size_t)128 * 256 * 2);

    hipMemsetAsync(counts, 0, (size_t)N * 4, stream);
    hipMemsetAsync(loss_acc, 0, 4, stream);
    count_edges_k<<<(E + 255) / 256, 256, 0, stream>>>(edst, counts, E);
    scan_k<<<1, 1024, 0, stream>>>(counts, row_start, cursor, inv_deg, N);
    fill_csr_k<<<(E + 255) / 256, 256, 0, stream>>>(esrc, edst, cursor, csr_src, E);

    prep_w_k<<<(2 * 128 * 128 + 255) / 256, 256, 0, stream>>>(Wl_i[0], Wr_i[0], Wt_i0, 128, 128);
    prep_w_k<<<(2 * 128 * 128 + 255) / 256, 256, 0, stream>>>(Wl_i[1], Wr_i[1], Wt_i1, 128, 128);
    prep_w_k<<<(2 * 256 * 256 + 255) / 256, 256, 0, stream>>>(Wl_m, Wr_m, Wt_m, 256, 256);
    prep_w_k<<<(2 * 256 * 64 + 255) / 256, 256, 0, stream>>>(Wl_o, Wr_o, Wt_o, 256, 64);

    const int RB = (N + 63) / 64;  // 782 row blocks
    const ushort* Wt_i[2] = {Wt_i0, Wt_i1};

    for (int k = 0; k < 2; ++k) {
        for (int ch = 0; ch < 2; ++ch) {
            const float* Xc = X + (size_t)(k * 2 + ch) * N * 128;
            gemm_mfma_k<true><<<dim3(RB, 2), 256, 0, stream>>>(Xc, 128, Wt_i[ch], V, R, 128, N);
            agg_k<2, 1, true, true><<<(N + 3) / 4, 256, 0, stream>>>(V, R, bl_i[ch], inv_deg, row_start, csr_src,
                                                                     xk + ch * 128, 256, N);
        }
        gemm_mfma_k<false><<<dim3(RB, 4), 256, 0, stream>>>(xk, 256, Wt_m, V, R, 256, N);
        agg_k<4, 1, true, true><<<(N + 3) / 4, 256, 0, stream>>>(V, R, bl_m, inv_deg, row_start, csr_src,
                                                                 xk, 256, N);
        gemm_mfma_k<false><<<dim3(RB, 1), 256, 0, stream>>>(xk, 256, Wt_o, V, R, 64, N);
        agg_k<1, 2, true, false><<<(N + 3) / 4, 256, 0, stream>>>(V, R, bl_o, inv_deg, row_start, csr_src,
                                                                  hk, 64, N);
        agg_k<1, 0, false, false><<<(N + 3) / 4, 256, 0, stream>>>(hk, nullptr, nullptr, inv_deg, row_start, csr_src,
                                                                   Ah, 64, N);
        head_ce_k<<<(N + 255) / 256, 256, 0, stream>>>(Ah, hk,
            Wl_t1 + (size_t)k * 64 * 12, bl_t1 + (size_t)k * 12, Wr_t1 + (size_t)k * 64 * 12,
            Wl_t2 + (size_t)k * 64 * 8,  bl_t2 + (size_t)k * 8,  Wr_t2 + (size_t)k * 64 * 8,
            Wl_t3 + (size_t)k * 64 * 5,  bl_t3 + (size_t)k * 5,  Wr_t3 + (size_t)k * 64 * 5,
            y + (size_t)k * N * 3, loss_acc, N);
    }
    finalize_k<<<1, 1, 0, stream>>>(loss_acc, (float*)d_out, N);
}